// Round 10
// baseline (215.552 us; speedup 1.0000x reference)
//
#include <hip/hip_runtime.h>
#include <math.h>

#define N_NODES 50000
#define N_EDGES 1600000
#define IN_CH   512
#define OUT_CH  48
#define XW_LD   64                   // xw row stride in ushorts -> 128B, one cache line
#define N_TILES (N_NODES / 16)       // 3125 row-tiles, exact

#define BSHIFT  6                    // 64 nodes per bucket
#define BNODES  64
#define NB      ((N_NODES + BNODES - 1) / BNODES)   // 782 buckets
#define ETILE   8192                 // edges per bin_edges block
#define CAP     2816                 // max edges per bucket handled by sort
#define CHUNK   128                  // edges per wave in seg_aggregate (divides N_EDGES)

typedef __attribute__((ext_vector_type(8))) short bf16x8;
typedef __attribute__((ext_vector_type(4))) float f32x4;

// fp32 -> bf16 (round-to-nearest-even), branch-free
static __device__ inline short f2bf(float x) {
    union { float f; unsigned u; } in; in.f = x;
    unsigned r = in.u + 0x7fffu + ((in.u >> 16) & 1u);
    return (short)(r >> 16);
}
static __device__ inline float bf2f(unsigned v16) {
    union { unsigned u; float f; } o; o.u = v16 << 16; return o.f;
}

// ---------------- Kernel 1: xw = features @ weight via bf16 MFMA ----------------
__global__ __launch_bounds__(256) void gemm_mfma(const float* __restrict__ f,
                                                 const float* __restrict__ w,
                                                 unsigned short* __restrict__ xw) {
    __shared__ bf16x8 sB[16 * 3 * 64];   // [s][t][lane], 48 KB

    int tid  = threadIdx.x;
    int lane = tid & 63;
    int wid  = tid >> 6;

    // stage B fragments: w[k][col] -> bf16, frag layout col=lane&15, k=8*(lane>>4)+j
    for (int idx = tid; idx < 16 * 3 * 64 * 8; idx += 256) {
        int j  = idx & 7;
        int ln = (idx >> 3) & 63;
        int st = idx >> 9;           // s*3 + t
        int t  = st % 3;
        int s  = st / 3;
        int k   = s * 32 + ((ln >> 4) << 3) + j;
        int col = t * 16 + (ln & 15);
        reinterpret_cast<short*>(sB)[idx] = f2bf(w[k * OUT_CH + col]);
    }
    __syncthreads();

    int tile = blockIdx.x * 4 + wid;
    if (tile >= N_TILES) return;

    int row = tile * 16 + (lane & 15);
    const float* fp = f + (size_t)row * IN_CH + ((lane >> 4) << 3);

    f32x4 acc0 = {0.f, 0.f, 0.f, 0.f};
    f32x4 acc1 = {0.f, 0.f, 0.f, 0.f};
    f32x4 acc2 = {0.f, 0.f, 0.f, 0.f};

    #pragma unroll 4
    for (int s = 0; s < 16; ++s) {
        float4 a0 = *reinterpret_cast<const float4*>(fp + s * 32);
        float4 a1 = *reinterpret_cast<const float4*>(fp + s * 32 + 4);
        bf16x8 a;
        a[0] = f2bf(a0.x); a[1] = f2bf(a0.y); a[2] = f2bf(a0.z); a[3] = f2bf(a0.w);
        a[4] = f2bf(a1.x); a[5] = f2bf(a1.y); a[6] = f2bf(a1.z); a[7] = f2bf(a1.w);
        bf16x8 b0 = sB[(s * 3 + 0) * 64 + lane];
        bf16x8 b1 = sB[(s * 3 + 1) * 64 + lane];
        bf16x8 b2 = sB[(s * 3 + 2) * 64 + lane];
        acc0 = __builtin_amdgcn_mfma_f32_16x16x32_bf16(a, b0, acc0, 0, 0, 0);
        acc1 = __builtin_amdgcn_mfma_f32_16x16x32_bf16(a, b1, acc1, 0, 0, 0);
        acc2 = __builtin_amdgcn_mfma_f32_16x16x32_bf16(a, b2, acc2, 0, 0, 0);
    }

    unsigned short* orow = xw + (size_t)tile * 16 * XW_LD;
    int c  = lane & 15;
    int r0 = (lane >> 4) * 4;
    #pragma unroll
    for (int r = 0; r < 4; ++r) {
        orow[(size_t)(r0 + r) * XW_LD +  0 + c] = (unsigned short)f2bf(acc0[r]);
        orow[(size_t)(r0 + r) * XW_LD + 16 + c] = (unsigned short)f2bf(acc1[r]);
        orow[(size_t)(r0 + r) * XW_LD + 32 + c] = (unsigned short)f2bf(acc2[r]);
    }
}

// ---------------- Kernel 2: per-bucket histogram (LDS-staged) ----------------
__global__ __launch_bounds__(256) void bucket_hist(const int* __restrict__ dst,
                                                   int* __restrict__ counts) {
    __shared__ int h[NB];
    for (int i = threadIdx.x; i < NB; i += blockDim.x) h[i] = 0;
    __syncthreads();
    for (int e = blockIdx.x * blockDim.x + threadIdx.x; e < N_EDGES;
         e += gridDim.x * blockDim.x)
        atomicAdd(&h[dst[e] >> BSHIFT], 1);
    __syncthreads();
    for (int i = threadIdx.x; i < NB; i += blockDim.x)
        if (h[i]) atomicAdd(&counts[i], h[i]);
}

// ---------------- Kernel 3: exclusive scan over NB buckets (1 block) ----------------
__global__ __launch_bounds__(1024) void bucket_scan(const int* __restrict__ counts,
                                                    int* __restrict__ base,
                                                    int* __restrict__ cursor) {
    __shared__ int sdata[1024];
    int t = threadIdx.x;
    int v = (t < NB) ? counts[t] : 0;
    sdata[t] = v;
    __syncthreads();
    for (int d = 1; d < 1024; d <<= 1) {
        int x = (t >= d) ? sdata[t - d] : 0;
        __syncthreads();
        sdata[t] += x;
        __syncthreads();
    }
    if (t < NB) { int e = sdata[t] - v; base[t] = e; cursor[t] = e; }
}

// ---------------- Kernel 4: LDS-staged binning (coalesced scatter) ----------------
__global__ __launch_bounds__(512) void bin_edges(const int* __restrict__ src,
                                                 const int* __restrict__ dst,
                                                 const float* __restrict__ ew,
                                                 int* __restrict__ cursor,
                                                 int2* __restrict__ epack) {
    __shared__ int   hist[NB];
    __shared__ int   loff[NB];
    __shared__ int   gbase[NB];
    __shared__ int   ssum[512];
    __shared__ int2  buf[ETILE];      // 64 KB
    __shared__ short bkt[ETILE];      // 16 KB

    int tid = threadIdx.x;
    int tileStart = blockIdx.x * ETILE;
    int tileN = N_EDGES - tileStart; if (tileN > ETILE) tileN = ETILE;

    for (int i = tid; i < NB; i += 512) hist[i] = 0;
    __syncthreads();

    // pass A: ranks via LDS histogram (cache src/dst/ew in registers)
    int   rank[ETILE / 512];
    int   dreg[ETILE / 512];
    int   sreg[ETILE / 512];
    float wreg[ETILE / 512];
    #pragma unroll
    for (int k = 0; k < ETILE / 512; ++k) {
        int e = tileStart + k * 512 + tid;
        dreg[k] = (e < N_EDGES) ? dst[e] : 0;
        sreg[k] = (e < N_EDGES) ? src[e] : 0;
        wreg[k] = (e < N_EDGES) ? ew[e]  : 0.f;
        rank[k] = (e < N_EDGES) ? atomicAdd(&hist[dreg[k] >> BSHIFT], 1) : 0;
    }
    __syncthreads();

    // reserve global space per bucket
    for (int i = tid; i < NB; i += 512) {
        int c = hist[i];
        gbase[i] = c ? atomicAdd(&cursor[i], c) : 0;
    }

    // exclusive scan of hist -> loff (2 entries per thread)
    int a0 = (2 * tid     < NB) ? hist[2 * tid]     : 0;
    int a1 = (2 * tid + 1 < NB) ? hist[2 * tid + 1] : 0;
    ssum[tid] = a0 + a1;
    __syncthreads();
    for (int d = 1; d < 512; d <<= 1) {
        int x = (tid >= d) ? ssum[tid - d] : 0;
        __syncthreads();
        ssum[tid] += x;
        __syncthreads();
    }
    int excl = ssum[tid] - (a0 + a1);
    if (2 * tid     < NB) loff[2 * tid]     = excl;
    if (2 * tid + 1 < NB) loff[2 * tid + 1] = excl + a0;
    __syncthreads();

    // pass B: stage edges into LDS in bucket order
    #pragma unroll
    for (int k = 0; k < ETILE / 512; ++k) {
        int e = tileStart + k * 512 + tid;
        if (e < N_EDGES) {
            int d = dreg[k];
            int b = d >> BSHIFT;
            int slot = loff[b] + rank[k];
            int2 p;
            p.x = (sreg[k] & 0xFFFF) | (d << 16);   // src 16b | full dst 16b
            p.y = __float_as_int(wreg[k]);
            buf[slot] = p;
            bkt[slot] = (short)b;
        }
    }
    __syncthreads();

    // streaming writeout: consecutive slots -> consecutive global positions
    for (int idx = tid; idx < tileN; idx += 512) {
        int b = bkt[idx];
        epack[gbase[b] + idx - loff[b]] = buf[idx];
    }
}

// ---------------- Kernel 5: in-bucket sort by node ----------------
__global__ __launch_bounds__(256) void sort_bucket(const int* __restrict__ base,
                                                   const int* __restrict__ cursor,
                                                   int2* __restrict__ epack) {
    __shared__ int2  A[CAP];      // 22.5 KB
    __shared__ int2  B[CAP];      // 22.5 KB
    __shared__ short rk[CAP];     // 5.6 KB
    __shared__ int   hist[BNODES];
    __shared__ int   loff[BNODES];

    int b  = blockIdx.x;
    int lo = base[b], hi = cursor[b];
    int len = hi - lo;
    if (len <= 0 || len > CAP) return;   // oversize: leave unsorted (agg still correct)

    int tid = threadIdx.x;
    if (tid < BNODES) hist[tid] = 0;
    for (int i = tid; i < len; i += 256) A[i] = epack[lo + i];
    __syncthreads();

    for (int i = tid; i < len; i += 256) {
        int key = (((unsigned)A[i].x) >> 16) & (BNODES - 1);
        rk[i] = (short)atomicAdd(&hist[key], 1);
    }
    __syncthreads();

    if (tid < BNODES) {           // wave 0: exclusive scan of 64 counters
        int v = hist[tid];
        int s = v;
        #pragma unroll
        for (int d = 1; d < 64; d <<= 1) {
            int t = __shfl_up(s, d);
            if (tid >= d) s += t;
        }
        loff[tid] = s - v;
    }
    __syncthreads();

    for (int i = tid; i < len; i += 256) {
        int key = (((unsigned)A[i].x) >> 16) & (BNODES - 1);
        B[loff[key] + rk[i]] = A[i];
    }
    __syncthreads();

    for (int i = tid; i < len; i += 256) epack[lo + i] = B[i];
}

// ---------------- Kernel 6: segmented reduction over sorted edges ----------------
// One wave per 128-edge chunk. Lane = eg*8 + s (eg = edge-in-batch 0..7,
// s = 16B slot 0..7). ONE dwordx4 gather fetches 8 edges' rows; 2-deep
// software pipeline keeps 16 lines in flight. Flushes transpose acc back to
// lane=channel layout and issue ONE wave-coalesced 48-lane atomic.
__global__ __launch_bounds__(256) void seg_aggregate(const int2* __restrict__ epack,
                                                     const unsigned short* __restrict__ xw,
                                                     float* __restrict__ out) {
    int wv   = (blockIdx.x * blockDim.x + threadIdx.x) >> 6;
    int lane = threadIdx.x & 63;
    int base = wv * CHUNK;
    if (base >= N_EDGES) return;          // CHUNK divides N_EDGES exactly
    int s  = lane & 7;                    // slot: channels s*8 .. s*8+7 (s<6 real)
    int eg = lane >> 3;                   // edge-in-batch 0..7

    // lane-held edges: 128 edges across 64 lanes
    int2 E0 = epack[base + lane];
    int2 E1 = epack[base + 64 + lane];

    float acc[8];
    #pragma unroll
    for (int i = 0; i < 8; ++i) acc[i] = 0.f;

    int cur = ((unsigned)__shfl(E0.x, 0)) >> 16;

    // coalesced flush: transpose (slot-major, replicated) -> lane=channel,
    // then one 48-lane atomic instruction.
    auto flushfn = [&](int node) {
        float v = 0.f;
        #pragma unroll
        for (int i = 0; i < 8; ++i) {
            float t = __shfl(acc[i], lane >> 3);
            if ((lane & 7) == i) v = t;
        }
        if (lane < OUT_CH) atomicAdd(&out[(size_t)node * OUT_CH + lane], v);
    };

    // 2-deep software pipeline over 16 batches of 8 edges
    int pxA, pwA, pxB, pwB;
    uint4 vA, vB;
    {
        pxA = __shfl(E0.x, eg);
        pwA = __shfl(E0.y, eg);
        vA  = *reinterpret_cast<const uint4*>(xw + (size_t)(pxA & 0xFFFF) * XW_LD + s * 8);
    }
    {
        pxB = __shfl(E0.x, 8 + eg);
        pwB = __shfl(E0.y, 8 + eg);
        vB  = *reinterpret_cast<const uint4*>(xw + (size_t)(pxB & 0xFFFF) * XW_LD + s * 8);
    }

    #pragma unroll
    for (int j = 0; j < 16; ++j) {
        int px, pw; uint4 v;
        if ((j & 1) == 0) { px = pxA; pw = pwA; v = vA; }
        else              { px = pxB; pw = pwB; v = vB; }

        // issue gather for batch j+2 into the freed slot (independent of process)
        if (j + 2 < 16) {
            int jj = (j + 2) * 8 + eg;
            int sx = (j + 2 < 8) ? E0.x : E1.x;
            int sy = (j + 2 < 8) ? E0.y : E1.y;
            int pxn = __shfl(sx, jj & 63);
            int pwn = __shfl(sy, jj & 63);
            uint4 vn = *reinterpret_cast<const uint4*>(
                xw + (size_t)(pxn & 0xFFFF) * XW_LD + s * 8);
            if ((j & 1) == 0) { pxA = pxn; pwA = pwn; vA = vn; }
            else              { pxB = pxn; pwB = pwn; vB = vn; }
        }

        // process current batch
        int   node = ((unsigned)px) >> 16;
        float wf   = __int_as_float(pw);
        float f[8];
        f[0] = bf2f(v.x & 0xFFFFu) * wf; f[1] = bf2f(v.x >> 16) * wf;
        f[2] = bf2f(v.y & 0xFFFFu) * wf; f[3] = bf2f(v.y >> 16) * wf;
        f[4] = bf2f(v.z & 0xFFFFu) * wf; f[5] = bf2f(v.z >> 16) * wf;
        f[6] = bf2f(v.w & 0xFFFFu) * wf; f[7] = bf2f(v.w >> 16) * wf;

        if (__all(node == cur)) {
            // whole batch in current run: reduce across the 8 edge-groups
            #pragma unroll
            for (int i = 0; i < 8; ++i) f[i] += __shfl_xor(f[i], 8);
            #pragma unroll
            for (int i = 0; i < 8; ++i) f[i] += __shfl_xor(f[i], 16);
            #pragma unroll
            for (int i = 0; i < 8; ++i) f[i] += __shfl_xor(f[i], 32);
            #pragma unroll
            for (int i = 0; i < 8; ++i) acc[i] += f[i];
        } else {
            // boundary batch: per-edge, wave-uniform flushes
            #pragma unroll
            for (int e = 0; e < 8; ++e) {
                int ne = __shfl(node, e << 3);       // node of edge e (uniform)
                if (ne != cur) {
                    flushfn(cur);
                    #pragma unroll
                    for (int i = 0; i < 8; ++i) acc[i] = 0.f;
                    cur = ne;
                }
                #pragma unroll
                for (int i = 0; i < 8; ++i)
                    acc[i] += __shfl(f[i], (e << 3) | s);
            }
        }
    }

    flushfn(cur);
}

// ---------------- Kernel 7: bias + log-softmax, in place, wave per node ----------------
__global__ __launch_bounds__(256) void lsm_rows(float* __restrict__ z,
                                                const float* __restrict__ bias) {
    int node = (blockIdx.x * blockDim.x + threadIdx.x) >> 6;
    int lane = threadIdx.x & 63;
    if (node >= N_NODES) return;
    bool ch = (lane < OUT_CH);

    float v = ch ? (z[(size_t)node * OUT_CH + lane] + bias[lane]) : -INFINITY;
    float m = v;
    #pragma unroll
    for (int d = 32; d >= 1; d >>= 1) m = fmaxf(m, __shfl_xor(m, d));
    float e = ch ? expf(v - m) : 0.f;
    float s = e;
    #pragma unroll
    for (int d = 32; d >= 1; d >>= 1) s += __shfl_xor(s, d);
    float lse = m + logf(s);
    if (ch) z[(size_t)node * OUT_CH + lane] = v - lse;
}

extern "C" void kernel_launch(void* const* d_in, const int* in_sizes, int n_in,
                              void* d_out, int out_size, void* d_ws, size_t ws_size,
                              hipStream_t stream) {
    const int*   edge_index = (const int*)d_in[0];
    const float* features   = (const float*)d_in[1];
    const float* eweights   = (const float*)d_in[2];
    const float* weight     = (const float*)d_in[3];
    const float* bias       = (const float*)d_in[4];

    const int* src = edge_index;            // edge_index[0, :]
    const int* dst = edge_index + N_EDGES;  // edge_index[1, :]

    float* out = (float*)d_out;

    // Workspace layout (bytes):
    //   xw (bf16, LD=64) @ 0 : 50000*64*2 = 6,400,000
    //   counts  @ 9,600,000 : NB*4
    //   base    @ 9,608,000 : NB*4
    //   cursor  @ 9,616,000 : NB*4
    //   epack   @ 9,624,000 : 12,800,000
    char* ws = (char*)d_ws;
    unsigned short* xw = (unsigned short*)(ws + 0);
    int*   counts = (int*)  (ws + 9600000);
    int*   base   = (int*)  (ws + 9608000);
    int*   cursor = (int*)  (ws + 9616000);
    int2*  epack  = (int2*) (ws + 9624000);

    hipMemsetAsync(counts, 0, NB * sizeof(int), stream);
    hipMemsetAsync(d_out, 0, (size_t)N_NODES * OUT_CH * sizeof(float), stream);

    // 1) xw = features @ weight  (bf16 MFMA, bf16 output)
    gemm_mfma<<<(N_TILES + 3) / 4, 256, 0, stream>>>(features, weight, xw);

    // 2) bucket binning (coarse, write-coalesced) + in-bucket sort
    bucket_hist<<<256, 256, 0, stream>>>(dst, counts);
    bucket_scan<<<1, 1024, 0, stream>>>(counts, base, cursor);
    bin_edges<<<(N_EDGES + ETILE - 1) / ETILE, 512, 0, stream>>>(src, dst, eweights,
                                                                 cursor, epack);
    sort_bucket<<<NB, 256, 0, stream>>>(base, cursor, epack);

    // 3) segmented reduction (wave per 128-edge chunk, batched gathers, 2-deep pipe)
    {
        int nWaves  = (N_EDGES + CHUNK - 1) / CHUNK;   // 12500
        int nBlocks = (nWaves + 3) / 4;
        seg_aggregate<<<nBlocks, 256, 0, stream>>>(epack, xw, out);
    }
    // 4) bias + log-softmax
    lsm_rows<<<(N_NODES + 3) / 4, 256, 0, stream>>>(out, bias);
}

// Round 11
// 175.182 us; speedup vs baseline: 1.2304x; 1.2304x over previous
//
#include <hip/hip_runtime.h>
#include <math.h>

#define N_NODES 50000
#define N_EDGES 1600000
#define IN_CH   512
#define OUT_CH  48
#define XW_LD   64                   // xw row stride in ushorts -> 128B, one cache line
#define N_TILES (N_NODES / 16)       // 3125 row-tiles, exact

#define BSHIFT  6                    // 64 nodes per bucket
#define BNODES  64
#define NB      ((N_NODES + BNODES - 1) / BNODES)   // 782 buckets
#define ETILE   8192                 // edges per bin_edges block
#define CAP     2816                 // max edges per bucket handled by sort
#define CHUNK   128                  // edges per wave in seg_aggregate (divides N_EDGES)

typedef __attribute__((ext_vector_type(8))) short bf16x8;
typedef __attribute__((ext_vector_type(4))) float f32x4;

// fp32 -> bf16 (round-to-nearest-even), branch-free
static __device__ inline short f2bf(float x) {
    union { float f; unsigned u; } in; in.f = x;
    unsigned r = in.u + 0x7fffu + ((in.u >> 16) & 1u);
    return (short)(r >> 16);
}
static __device__ inline float bf2f(unsigned v16) {
    union { unsigned u; float f; } o; o.u = v16 << 16; return o.f;
}

// ---------------- Kernel 1: xw = features @ weight via bf16 MFMA ----------------
__global__ __launch_bounds__(256) void gemm_mfma(const float* __restrict__ f,
                                                 const float* __restrict__ w,
                                                 unsigned short* __restrict__ xw) {
    __shared__ bf16x8 sB[16 * 3 * 64];   // [s][t][lane], 48 KB

    int tid  = threadIdx.x;
    int lane = tid & 63;
    int wid  = tid >> 6;

    // stage B fragments: w[k][col] -> bf16, frag layout col=lane&15, k=8*(lane>>4)+j
    for (int idx = tid; idx < 16 * 3 * 64 * 8; idx += 256) {
        int j  = idx & 7;
        int ln = (idx >> 3) & 63;
        int st = idx >> 9;           // s*3 + t
        int t  = st % 3;
        int s  = st / 3;
        int k   = s * 32 + ((ln >> 4) << 3) + j;
        int col = t * 16 + (ln & 15);
        reinterpret_cast<short*>(sB)[idx] = f2bf(w[k * OUT_CH + col]);
    }
    __syncthreads();

    int tile = blockIdx.x * 4 + wid;
    if (tile >= N_TILES) return;

    int row = tile * 16 + (lane & 15);
    const float* fp = f + (size_t)row * IN_CH + ((lane >> 4) << 3);

    f32x4 acc0 = {0.f, 0.f, 0.f, 0.f};
    f32x4 acc1 = {0.f, 0.f, 0.f, 0.f};
    f32x4 acc2 = {0.f, 0.f, 0.f, 0.f};

    #pragma unroll 4
    for (int s = 0; s < 16; ++s) {
        float4 a0 = *reinterpret_cast<const float4*>(fp + s * 32);
        float4 a1 = *reinterpret_cast<const float4*>(fp + s * 32 + 4);
        bf16x8 a;
        a[0] = f2bf(a0.x); a[1] = f2bf(a0.y); a[2] = f2bf(a0.z); a[3] = f2bf(a0.w);
        a[4] = f2bf(a1.x); a[5] = f2bf(a1.y); a[6] = f2bf(a1.z); a[7] = f2bf(a1.w);
        bf16x8 b0 = sB[(s * 3 + 0) * 64 + lane];
        bf16x8 b1 = sB[(s * 3 + 1) * 64 + lane];
        bf16x8 b2 = sB[(s * 3 + 2) * 64 + lane];
        acc0 = __builtin_amdgcn_mfma_f32_16x16x32_bf16(a, b0, acc0, 0, 0, 0);
        acc1 = __builtin_amdgcn_mfma_f32_16x16x32_bf16(a, b1, acc1, 0, 0, 0);
        acc2 = __builtin_amdgcn_mfma_f32_16x16x32_bf16(a, b2, acc2, 0, 0, 0);
    }

    unsigned short* orow = xw + (size_t)tile * 16 * XW_LD;
    int c  = lane & 15;
    int r0 = (lane >> 4) * 4;
    #pragma unroll
    for (int r = 0; r < 4; ++r) {
        orow[(size_t)(r0 + r) * XW_LD +  0 + c] = (unsigned short)f2bf(acc0[r]);
        orow[(size_t)(r0 + r) * XW_LD + 16 + c] = (unsigned short)f2bf(acc1[r]);
        orow[(size_t)(r0 + r) * XW_LD + 32 + c] = (unsigned short)f2bf(acc2[r]);
    }
}

// ---------------- Kernel 2: per-bucket histogram (LDS-staged) ----------------
__global__ __launch_bounds__(256) void bucket_hist(const int* __restrict__ dst,
                                                   int* __restrict__ counts) {
    __shared__ int h[NB];
    for (int i = threadIdx.x; i < NB; i += blockDim.x) h[i] = 0;
    __syncthreads();
    for (int e = blockIdx.x * blockDim.x + threadIdx.x; e < N_EDGES;
         e += gridDim.x * blockDim.x)
        atomicAdd(&h[dst[e] >> BSHIFT], 1);
    __syncthreads();
    for (int i = threadIdx.x; i < NB; i += blockDim.x)
        if (h[i]) atomicAdd(&counts[i], h[i]);
}

// ---------------- Kernel 3: exclusive scan over NB buckets (1 block) ----------------
__global__ __launch_bounds__(1024) void bucket_scan(const int* __restrict__ counts,
                                                    int* __restrict__ base,
                                                    int* __restrict__ cursor) {
    __shared__ int sdata[1024];
    int t = threadIdx.x;
    int v = (t < NB) ? counts[t] : 0;
    sdata[t] = v;
    __syncthreads();
    for (int d = 1; d < 1024; d <<= 1) {
        int x = (t >= d) ? sdata[t - d] : 0;
        __syncthreads();
        sdata[t] += x;
        __syncthreads();
    }
    if (t < NB) { int e = sdata[t] - v; base[t] = e; cursor[t] = e; }
}

// ---------------- Kernel 4: LDS-staged binning (coalesced scatter) ----------------
__global__ __launch_bounds__(512) void bin_edges(const int* __restrict__ src,
                                                 const int* __restrict__ dst,
                                                 const float* __restrict__ ew,
                                                 int* __restrict__ cursor,
                                                 int2* __restrict__ epack) {
    __shared__ int   hist[NB];
    __shared__ int   loff[NB];
    __shared__ int   gbase[NB];
    __shared__ int   ssum[512];
    __shared__ int2  buf[ETILE];      // 64 KB
    __shared__ short bkt[ETILE];      // 16 KB

    int tid = threadIdx.x;
    int tileStart = blockIdx.x * ETILE;
    int tileN = N_EDGES - tileStart; if (tileN > ETILE) tileN = ETILE;

    for (int i = tid; i < NB; i += 512) hist[i] = 0;
    __syncthreads();

    // pass A: ranks via LDS histogram (cache dst in registers)
    int rank[ETILE / 512];
    int dreg[ETILE / 512];
    #pragma unroll
    for (int k = 0; k < ETILE / 512; ++k) {
        int e = tileStart + k * 512 + tid;
        dreg[k] = (e < N_EDGES) ? dst[e] : 0;
        rank[k] = (e < N_EDGES) ? atomicAdd(&hist[dreg[k] >> BSHIFT], 1) : 0;
    }
    __syncthreads();

    // reserve global space per bucket
    for (int i = tid; i < NB; i += 512) {
        int c = hist[i];
        gbase[i] = c ? atomicAdd(&cursor[i], c) : 0;
    }

    // exclusive scan of hist -> loff (2 entries per thread)
    int a0 = (2 * tid     < NB) ? hist[2 * tid]     : 0;
    int a1 = (2 * tid + 1 < NB) ? hist[2 * tid + 1] : 0;
    ssum[tid] = a0 + a1;
    __syncthreads();
    for (int d = 1; d < 512; d <<= 1) {
        int x = (tid >= d) ? ssum[tid - d] : 0;
        __syncthreads();
        ssum[tid] += x;
        __syncthreads();
    }
    int excl = ssum[tid] - (a0 + a1);
    if (2 * tid     < NB) loff[2 * tid]     = excl;
    if (2 * tid + 1 < NB) loff[2 * tid + 1] = excl + a0;
    __syncthreads();

    // pass B: stage edges into LDS in bucket order
    #pragma unroll
    for (int k = 0; k < ETILE / 512; ++k) {
        int e = tileStart + k * 512 + tid;
        if (e < N_EDGES) {
            int d = dreg[k];
            int b = d >> BSHIFT;
            int slot = loff[b] + rank[k];
            int2 p;
            p.x = (src[e] & 0xFFFF) | (d << 16);   // src 16b | full dst 16b
            p.y = __float_as_int(ew[e]);
            buf[slot] = p;
            bkt[slot] = (short)b;
        }
    }
    __syncthreads();

    // streaming writeout: consecutive slots -> consecutive global positions
    for (int idx = tid; idx < tileN; idx += 512) {
        int b = bkt[idx];
        epack[gbase[b] + idx - loff[b]] = buf[idx];
    }
}

// ---------------- Kernel 5: in-bucket sort by node ----------------
__global__ __launch_bounds__(256) void sort_bucket(const int* __restrict__ base,
                                                   const int* __restrict__ cursor,
                                                   int2* __restrict__ epack) {
    __shared__ int2  A[CAP];      // 22.5 KB
    __shared__ int2  B[CAP];      // 22.5 KB
    __shared__ short rk[CAP];     // 5.6 KB
    __shared__ int   hist[BNODES];
    __shared__ int   loff[BNODES];

    int b  = blockIdx.x;
    int lo = base[b], hi = cursor[b];
    int len = hi - lo;
    if (len <= 0 || len > CAP) return;   // oversize: leave unsorted (agg still correct)

    int tid = threadIdx.x;
    if (tid < BNODES) hist[tid] = 0;
    for (int i = tid; i < len; i += 256) A[i] = epack[lo + i];
    __syncthreads();

    for (int i = tid; i < len; i += 256) {
        int key = (((unsigned)A[i].x) >> 16) & (BNODES - 1);
        rk[i] = (short)atomicAdd(&hist[key], 1);
    }
    __syncthreads();

    if (tid < BNODES) {           // wave 0: exclusive scan of 64 counters
        int v = hist[tid];
        int s = v;
        #pragma unroll
        for (int d = 1; d < 64; d <<= 1) {
            int t = __shfl_up(s, d);
            if (tid >= d) s += t;
        }
        loff[tid] = s - v;
    }
    __syncthreads();

    for (int i = tid; i < len; i += 256) {
        int key = (((unsigned)A[i].x) >> 16) & (BNODES - 1);
        B[loff[key] + rk[i]] = A[i];
    }
    __syncthreads();

    for (int i = tid; i < len; i += 256) epack[lo + i] = B[i];
}

// ---------------- Kernel 6: segmented reduction over sorted edges ----------------
// One wave per 128-edge chunk, TWO independent half-wave streams:
// half h = lane>=32 processes edges base+2t+h (t=0..63); cp = lane&31 is the
// channel pair (cp<24 real). One dword load per lane = 2 bf16 channels; one
// load instruction covers both halves = 2 edges = 2 cache lines. 8-deep
// double-buffered pipeline (all indices compile-time) = 16 lines in flight.
// Runs flush independently per half via fp32 atomics (safe).
__global__ __launch_bounds__(256) void seg_aggregate(const int2* __restrict__ epack,
                                                     const unsigned short* __restrict__ xw,
                                                     float* __restrict__ out) {
    int wv   = (blockIdx.x * blockDim.x + threadIdx.x) >> 6;
    int lane = threadIdx.x & 63;
    int base = wv * CHUNK;
    if (base >= N_EDGES) return;          // CHUNK divides N_EDGES exactly
    int h  = lane >> 5;                   // half: 0 -> even edges, 1 -> odd edges
    int cp = lane & 31;                   // channel pair (cp<24 real, rest pad)
    bool act = (cp < 24);

    // lane-held edges: 128 edges across 64 lanes
    int2 E0 = epack[base + lane];
    int2 E1 = epack[base + 64 + lane];

    float ax = 0.f, ay = 0.f;
    int cur = ((unsigned)__shfl(E0.x, h)) >> 16;   // node of this half's first edge

    int px[2][8]; float pw[2][8]; unsigned u[2][8];

    // prime block 0 (steps 0..7)
    #pragma unroll
    for (int k = 0; k < 8; ++k) {
        int idx = ((2 * k) & 63) | h;              // edge 2k+h lives in E0
        px[0][k] = __shfl(E0.x, idx);
        pw[0][k] = __int_as_float(__shfl(E0.y, idx));
    }
    #pragma unroll
    for (int k = 0; k < 8; ++k)
        u[0][k] = *reinterpret_cast<const unsigned*>(
            xw + (size_t)(px[0][k] & 0xFFFF) * XW_LD + (cp << 1));

    #pragma unroll
    for (int j = 0; j < 8; ++j) {                  // 8 blocks x 8 steps = 64 steps
        const int cb = j & 1, nb = cb ^ 1;
        if (j + 1 < 8) {
            #pragma unroll
            for (int k = 0; k < 8; ++k) {
                int t  = (j + 1) * 8 + k;          // step 8..63 (compile-time)
                int sx = (t < 32) ? E0.x : E1.x;
                int sy = (t < 32) ? E0.y : E1.y;
                int idx = ((2 * t) & 63) | h;
                px[nb][k] = __shfl(sx, idx);
                pw[nb][k] = __int_as_float(__shfl(sy, idx));
            }
            #pragma unroll
            for (int k = 0; k < 8; ++k)
                u[nb][k] = *reinterpret_cast<const unsigned*>(
                    xw + (size_t)(px[nb][k] & 0xFFFF) * XW_LD + (cp << 1));
        }
        #pragma unroll
        for (int k = 0; k < 8; ++k) {
            int node = ((unsigned)px[cb][k]) >> 16;
            if (node != cur) {                     // uniform within each half
                if (act) {
                    atomicAdd(&out[(size_t)cur * OUT_CH + (cp << 1)    ], ax);
                    atomicAdd(&out[(size_t)cur * OUT_CH + (cp << 1) + 1], ay);
                }
                ax = 0.f; ay = 0.f; cur = node;
            }
            float    wf = pw[cb][k];
            unsigned uu = u[cb][k];
            ax = fmaf(wf, bf2f(uu & 0xFFFFu), ax);
            ay = fmaf(wf, bf2f(uu >> 16), ay);
        }
    }

    if (act) {
        atomicAdd(&out[(size_t)cur * OUT_CH + (cp << 1)    ], ax);
        atomicAdd(&out[(size_t)cur * OUT_CH + (cp << 1) + 1], ay);
    }
}

// ---------------- Kernel 7: bias + log-softmax, in place, wave per node ----------------
__global__ __launch_bounds__(256) void lsm_rows(float* __restrict__ z,
                                                const float* __restrict__ bias) {
    int node = (blockIdx.x * blockDim.x + threadIdx.x) >> 6;
    int lane = threadIdx.x & 63;
    if (node >= N_NODES) return;
    bool ch = (lane < OUT_CH);

    float v = ch ? (z[(size_t)node * OUT_CH + lane] + bias[lane]) : -INFINITY;
    float m = v;
    #pragma unroll
    for (int d = 32; d >= 1; d >>= 1) m = fmaxf(m, __shfl_xor(m, d));
    float e = ch ? expf(v - m) : 0.f;
    float s = e;
    #pragma unroll
    for (int d = 32; d >= 1; d >>= 1) s += __shfl_xor(s, d);
    float lse = m + logf(s);
    if (ch) z[(size_t)node * OUT_CH + lane] = v - lse;
}

extern "C" void kernel_launch(void* const* d_in, const int* in_sizes, int n_in,
                              void* d_out, int out_size, void* d_ws, size_t ws_size,
                              hipStream_t stream) {
    const int*   edge_index = (const int*)d_in[0];
    const float* features   = (const float*)d_in[1];
    const float* eweights   = (const float*)d_in[2];
    const float* weight     = (const float*)d_in[3];
    const float* bias       = (const float*)d_in[4];

    const int* src = edge_index;            // edge_index[0, :]
    const int* dst = edge_index + N_EDGES;  // edge_index[1, :]

    float* out = (float*)d_out;

    // Workspace layout (bytes):
    //   xw (bf16, LD=64) @ 0 : 50000*64*2 = 6,400,000
    //   counts  @ 9,600,000 : NB*4
    //   base    @ 9,608,000 : NB*4
    //   cursor  @ 9,616,000 : NB*4
    //   epack   @ 9,624,000 : 12,800,000
    char* ws = (char*)d_ws;
    unsigned short* xw = (unsigned short*)(ws + 0);
    int*   counts = (int*)  (ws + 9600000);
    int*   base   = (int*)  (ws + 9608000);
    int*   cursor = (int*)  (ws + 9616000);
    int2*  epack  = (int2*) (ws + 9624000);

    hipMemsetAsync(counts, 0, NB * sizeof(int), stream);
    hipMemsetAsync(d_out, 0, (size_t)N_NODES * OUT_CH * sizeof(float), stream);

    // 1) xw = features @ weight  (bf16 MFMA, bf16 output)
    gemm_mfma<<<(N_TILES + 3) / 4, 256, 0, stream>>>(features, weight, xw);

    // 2) bucket binning (coarse, write-coalesced) + in-bucket sort
    bucket_hist<<<256, 256, 0, stream>>>(dst, counts);
    bucket_scan<<<1, 1024, 0, stream>>>(counts, base, cursor);
    bin_edges<<<(N_EDGES + ETILE - 1) / ETILE, 512, 0, stream>>>(src, dst, eweights,
                                                                 cursor, epack);
    sort_bucket<<<NB, 256, 0, stream>>>(base, cursor, epack);

    // 3) segmented reduction (wave per 128-edge chunk, paired half-wave streams)
    {
        int nWaves  = (N_EDGES + CHUNK - 1) / CHUNK;   // 12500
        int nBlocks = (nWaves + 3) / 4;
        seg_aggregate<<<nBlocks, 256, 0, stream>>>(epack, xw, out);
    }
    // 4) bias + log-softmax
    lsm_rows<<<(N_NODES + 3) / 4, 256, 0, stream>>>(out, bias);
}

// Round 12
// 153.205 us; speedup vs baseline: 1.4070x; 1.1435x over previous
//
#include <hip/hip_runtime.h>
#include <math.h>

#define N_NODES 50000
#define N_EDGES 1600000
#define IN_CH   512
#define OUT_CH  48
#define XW_LD   64                   // xw row stride in ushorts -> 128B, one cache line
#define N_TILES (N_NODES / 16)       // 3125 row-tiles, exact

#define BSHIFT  6                    // 64 nodes per bucket
#define BNODES  64
#define NB      ((N_NODES + BNODES - 1) / BNODES)   // 782 buckets
#define ETILE   8192                 // edges per bin_edges block
#define CAP     2816                 // max edges per bucket handled by sort
#define CHUNK   128                  // edges per wave in seg_aggregate (divides N_EDGES)

#define BFRAG_SHORTS (16 * 3 * 64 * 8)   // 24576 shorts = 48 KB fragment image of B

typedef __attribute__((ext_vector_type(8))) short bf16x8;
typedef __attribute__((ext_vector_type(4))) float f32x4;

// fp32 -> bf16 (round-to-nearest-even), branch-free
static __device__ inline short f2bf(float x) {
    union { float f; unsigned u; } in; in.f = x;
    unsigned r = in.u + 0x7fffu + ((in.u >> 16) & 1u);
    return (short)(r >> 16);
}
static __device__ inline float bf2f(unsigned v16) {
    union { unsigned u; float f; } o; o.u = v16 << 16; return o.f;
}

// ---------------- Kernel 0: pre-format B into MFMA fragment layout (once) ----------------
// wfrag[((s*3+t)*64 + ln)*8 + j] = bf16(w[k][col]), k = s*32 + ((ln>>4)<<3) + j,
// col = t*16 + (ln&15). Coalesced float4 reads of w (48 cols, 4 | 48).
__global__ __launch_bounds__(256) void prep_bfrag(const float* __restrict__ w,
                                                  unsigned short* __restrict__ wfrag) {
    int i = blockIdx.x * blockDim.x + threadIdx.x;       // one float4 per thread
    if (i >= IN_CH * OUT_CH / 4) return;
    int flat = i * 4;
    int k   = flat / OUT_CH;
    int col = flat % OUT_CH;
    float4 v = *reinterpret_cast<const float4*>(w + flat);
    int s = k >> 5, j = k & 7, q = (k >> 3) & 3;
    float vv[4] = {v.x, v.y, v.z, v.w};
    #pragma unroll
    for (int c = 0; c < 4; ++c) {
        int cc = col + c;
        int t  = cc >> 4;
        int ln = (cc & 15) | (q << 4);
        wfrag[((s * 3 + t) * 64 + ln) * 8 + j] = (unsigned short)f2bf(vv[c]);
    }
}

// ---------------- Kernel 1: xw = features @ weight via bf16 MFMA ----------------
// B fragments staged from pre-formatted wfrag with linear dwordx4 copies.
// A loads 2-deep software-pipelined.
__global__ __launch_bounds__(256) void gemm_mfma(const float* __restrict__ f,
                                                 const unsigned short* __restrict__ wfrag,
                                                 unsigned short* __restrict__ xw) {
    __shared__ short sBl[BFRAG_SHORTS];   // 48 KB, linear copy of wfrag

    int tid  = threadIdx.x;
    int lane = tid & 63;
    int wid  = tid >> 6;

    {
        const uint4* gw = reinterpret_cast<const uint4*>(wfrag);
        uint4*       sw = reinterpret_cast<uint4*>(sBl);
        #pragma unroll
        for (int i = 0; i < BFRAG_SHORTS / 8 / 256; ++i)   // 12 iterations
            sw[i * 256 + tid] = gw[i * 256 + tid];
    }
    __syncthreads();

    int tile = blockIdx.x * 4 + wid;
    if (tile >= N_TILES) return;

    const bf16x8* sB = reinterpret_cast<const bf16x8*>(sBl);

    int row = tile * 16 + (lane & 15);
    const float* fp = f + (size_t)row * IN_CH + ((lane >> 4) << 3);

    f32x4 acc0 = {0.f, 0.f, 0.f, 0.f};
    f32x4 acc1 = {0.f, 0.f, 0.f, 0.f};
    f32x4 acc2 = {0.f, 0.f, 0.f, 0.f};

    float4 a0[2], a1[2];
    a0[0] = *reinterpret_cast<const float4*>(fp);
    a1[0] = *reinterpret_cast<const float4*>(fp + 4);

    #pragma unroll
    for (int s = 0; s < 16; ++s) {
        const int cb = s & 1, nb = cb ^ 1;
        if (s + 1 < 16) {                                  // prefetch next K-step
            a0[nb] = *reinterpret_cast<const float4*>(fp + (s + 1) * 32);
            a1[nb] = *reinterpret_cast<const float4*>(fp + (s + 1) * 32 + 4);
        }
        bf16x8 a;
        a[0] = f2bf(a0[cb].x); a[1] = f2bf(a0[cb].y);
        a[2] = f2bf(a0[cb].z); a[3] = f2bf(a0[cb].w);
        a[4] = f2bf(a1[cb].x); a[5] = f2bf(a1[cb].y);
        a[6] = f2bf(a1[cb].z); a[7] = f2bf(a1[cb].w);
        bf16x8 b0 = sB[(s * 3 + 0) * 64 + lane];
        bf16x8 b1 = sB[(s * 3 + 1) * 64 + lane];
        bf16x8 b2 = sB[(s * 3 + 2) * 64 + lane];
        acc0 = __builtin_amdgcn_mfma_f32_16x16x32_bf16(a, b0, acc0, 0, 0, 0);
        acc1 = __builtin_amdgcn_mfma_f32_16x16x32_bf16(a, b1, acc1, 0, 0, 0);
        acc2 = __builtin_amdgcn_mfma_f32_16x16x32_bf16(a, b2, acc2, 0, 0, 0);
    }

    unsigned short* orow = xw + (size_t)tile * 16 * XW_LD;
    int c  = lane & 15;
    int r0 = (lane >> 4) * 4;
    #pragma unroll
    for (int r = 0; r < 4; ++r) {
        orow[(size_t)(r0 + r) * XW_LD +  0 + c] = (unsigned short)f2bf(acc0[r]);
        orow[(size_t)(r0 + r) * XW_LD + 16 + c] = (unsigned short)f2bf(acc1[r]);
        orow[(size_t)(r0 + r) * XW_LD + 32 + c] = (unsigned short)f2bf(acc2[r]);
    }
}

// ---------------- Kernel 2: per-bucket histogram (LDS-staged) ----------------
__global__ __launch_bounds__(256) void bucket_hist(const int* __restrict__ dst,
                                                   int* __restrict__ counts) {
    __shared__ int h[NB];
    for (int i = threadIdx.x; i < NB; i += blockDim.x) h[i] = 0;
    __syncthreads();
    for (int e = blockIdx.x * blockDim.x + threadIdx.x; e < N_EDGES;
         e += gridDim.x * blockDim.x)
        atomicAdd(&h[dst[e] >> BSHIFT], 1);
    __syncthreads();
    for (int i = threadIdx.x; i < NB; i += blockDim.x)
        if (h[i]) atomicAdd(&counts[i], h[i]);
}

// ---------------- Kernel 3: exclusive scan over NB buckets (1 block) ----------------
__global__ __launch_bounds__(1024) void bucket_scan(const int* __restrict__ counts,
                                                    int* __restrict__ base,
                                                    int* __restrict__ cursor) {
    __shared__ int sdata[1024];
    int t = threadIdx.x;
    int v = (t < NB) ? counts[t] : 0;
    sdata[t] = v;
    __syncthreads();
    for (int d = 1; d < 1024; d <<= 1) {
        int x = (t >= d) ? sdata[t - d] : 0;
        __syncthreads();
        sdata[t] += x;
        __syncthreads();
    }
    if (t < NB) { int e = sdata[t] - v; base[t] = e; cursor[t] = e; }
}

// ---------------- Kernel 4: LDS-staged binning (coalesced scatter) ----------------
__global__ __launch_bounds__(512) void bin_edges(const int* __restrict__ src,
                                                 const int* __restrict__ dst,
                                                 const float* __restrict__ ew,
                                                 int* __restrict__ cursor,
                                                 int2* __restrict__ epack) {
    __shared__ int   hist[NB];
    __shared__ int   loff[NB];
    __shared__ int   gbase[NB];
    __shared__ int   ssum[512];
    __shared__ int2  buf[ETILE];      // 64 KB
    __shared__ short bkt[ETILE];      // 16 KB

    int tid = threadIdx.x;
    int tileStart = blockIdx.x * ETILE;
    int tileN = N_EDGES - tileStart; if (tileN > ETILE) tileN = ETILE;

    for (int i = tid; i < NB; i += 512) hist[i] = 0;
    __syncthreads();

    // pass A: ranks via LDS histogram (cache dst in registers)
    int rank[ETILE / 512];
    int dreg[ETILE / 512];
    #pragma unroll
    for (int k = 0; k < ETILE / 512; ++k) {
        int e = tileStart + k * 512 + tid;
        dreg[k] = (e < N_EDGES) ? dst[e] : 0;
        rank[k] = (e < N_EDGES) ? atomicAdd(&hist[dreg[k] >> BSHIFT], 1) : 0;
    }
    __syncthreads();

    // reserve global space per bucket
    for (int i = tid; i < NB; i += 512) {
        int c = hist[i];
        gbase[i] = c ? atomicAdd(&cursor[i], c) : 0;
    }

    // exclusive scan of hist -> loff (2 entries per thread)
    int a0 = (2 * tid     < NB) ? hist[2 * tid]     : 0;
    int a1 = (2 * tid + 1 < NB) ? hist[2 * tid + 1] : 0;
    ssum[tid] = a0 + a1;
    __syncthreads();
    for (int d = 1; d < 512; d <<= 1) {
        int x = (tid >= d) ? ssum[tid - d] : 0;
        __syncthreads();
        ssum[tid] += x;
        __syncthreads();
    }
    int excl = ssum[tid] - (a0 + a1);
    if (2 * tid     < NB) loff[2 * tid]     = excl;
    if (2 * tid + 1 < NB) loff[2 * tid + 1] = excl + a0;
    __syncthreads();

    // pass B: stage edges into LDS in bucket order
    #pragma unroll
    for (int k = 0; k < ETILE / 512; ++k) {
        int e = tileStart + k * 512 + tid;
        if (e < N_EDGES) {
            int d = dreg[k];
            int b = d >> BSHIFT;
            int slot = loff[b] + rank[k];
            int2 p;
            p.x = (src[e] & 0xFFFF) | (d << 16);   // src 16b | full dst 16b
            p.y = __float_as_int(ew[e]);
            buf[slot] = p;
            bkt[slot] = (short)b;
        }
    }
    __syncthreads();

    // streaming writeout: consecutive slots -> consecutive global positions
    for (int idx = tid; idx < tileN; idx += 512) {
        int b = bkt[idx];
        epack[gbase[b] + idx - loff[b]] = buf[idx];
    }
}

// ---------------- Kernel 5: in-bucket sort by node ----------------
__global__ __launch_bounds__(256) void sort_bucket(const int* __restrict__ base,
                                                   const int* __restrict__ cursor,
                                                   int2* __restrict__ epack) {
    __shared__ int2  A[CAP];      // 22.5 KB
    __shared__ int2  B[CAP];      // 22.5 KB
    __shared__ short rk[CAP];     // 5.6 KB
    __shared__ int   hist[BNODES];
    __shared__ int   loff[BNODES];

    int b  = blockIdx.x;
    int lo = base[b], hi = cursor[b];
    int len = hi - lo;
    if (len <= 0 || len > CAP) return;   // oversize: leave unsorted (agg still correct)

    int tid = threadIdx.x;
    if (tid < BNODES) hist[tid] = 0;
    for (int i = tid; i < len; i += 256) A[i] = epack[lo + i];
    __syncthreads();

    for (int i = tid; i < len; i += 256) {
        int key = (((unsigned)A[i].x) >> 16) & (BNODES - 1);
        rk[i] = (short)atomicAdd(&hist[key], 1);
    }
    __syncthreads();

    if (tid < BNODES) {           // wave 0: exclusive scan of 64 counters
        int v = hist[tid];
        int s = v;
        #pragma unroll
        for (int d = 1; d < 64; d <<= 1) {
            int t = __shfl_up(s, d);
            if (tid >= d) s += t;
        }
        loff[tid] = s - v;
    }
    __syncthreads();

    for (int i = tid; i < len; i += 256) {
        int key = (((unsigned)A[i].x) >> 16) & (BNODES - 1);
        B[loff[key] + rk[i]] = A[i];
    }
    __syncthreads();

    for (int i = tid; i < len; i += 256) epack[lo + i] = B[i];
}

// ---------------- Kernel 6: segmented reduction over sorted edges ----------------
// One wave per 128-edge chunk, TWO independent half-wave streams (see r10).
__global__ __launch_bounds__(256) void seg_aggregate(const int2* __restrict__ epack,
                                                     const unsigned short* __restrict__ xw,
                                                     float* __restrict__ out) {
    int wv   = (blockIdx.x * blockDim.x + threadIdx.x) >> 6;
    int lane = threadIdx.x & 63;
    int base = wv * CHUNK;
    if (base >= N_EDGES) return;          // CHUNK divides N_EDGES exactly
    int h  = lane >> 5;                   // half: 0 -> even edges, 1 -> odd edges
    int cp = lane & 31;                   // channel pair (cp<24 real, rest pad)
    bool act = (cp < 24);

    int2 E0 = epack[base + lane];
    int2 E1 = epack[base + 64 + lane];

    float ax = 0.f, ay = 0.f;
    int cur = ((unsigned)__shfl(E0.x, h)) >> 16;

    int px[2][8]; float pw[2][8]; unsigned u[2][8];

    #pragma unroll
    for (int k = 0; k < 8; ++k) {
        int idx = ((2 * k) & 63) | h;
        px[0][k] = __shfl(E0.x, idx);
        pw[0][k] = __int_as_float(__shfl(E0.y, idx));
    }
    #pragma unroll
    for (int k = 0; k < 8; ++k)
        u[0][k] = *reinterpret_cast<const unsigned*>(
            xw + (size_t)(px[0][k] & 0xFFFF) * XW_LD + (cp << 1));

    #pragma unroll
    for (int j = 0; j < 8; ++j) {
        const int cb = j & 1, nb = cb ^ 1;
        if (j + 1 < 8) {
            #pragma unroll
            for (int k = 0; k < 8; ++k) {
                int t  = (j + 1) * 8 + k;
                int sx = (t < 32) ? E0.x : E1.x;
                int sy = (t < 32) ? E0.y : E1.y;
                int idx = ((2 * t) & 63) | h;
                px[nb][k] = __shfl(sx, idx);
                pw[nb][k] = __int_as_float(__shfl(sy, idx));
            }
            #pragma unroll
            for (int k = 0; k < 8; ++k)
                u[nb][k] = *reinterpret_cast<const unsigned*>(
                    xw + (size_t)(px[nb][k] & 0xFFFF) * XW_LD + (cp << 1));
        }
        #pragma unroll
        for (int k = 0; k < 8; ++k) {
            int node = ((unsigned)px[cb][k]) >> 16;
            if (node != cur) {
                if (act) {
                    atomicAdd(&out[(size_t)cur * OUT_CH + (cp << 1)    ], ax);
                    atomicAdd(&out[(size_t)cur * OUT_CH + (cp << 1) + 1], ay);
                }
                ax = 0.f; ay = 0.f; cur = node;
            }
            float    wf = pw[cb][k];
            unsigned uu = u[cb][k];
            ax = fmaf(wf, bf2f(uu & 0xFFFFu), ax);
            ay = fmaf(wf, bf2f(uu >> 16), ay);
        }
    }

    if (act) {
        atomicAdd(&out[(size_t)cur * OUT_CH + (cp << 1)    ], ax);
        atomicAdd(&out[(size_t)cur * OUT_CH + (cp << 1) + 1], ay);
    }
}

// ---------------- Kernel 7: bias + log-softmax, in place, wave per node ----------------
__global__ __launch_bounds__(256) void lsm_rows(float* __restrict__ z,
                                                const float* __restrict__ bias) {
    int node = (blockIdx.x * blockDim.x + threadIdx.x) >> 6;
    int lane = threadIdx.x & 63;
    if (node >= N_NODES) return;
    bool ch = (lane < OUT_CH);

    float v = ch ? (z[(size_t)node * OUT_CH + lane] + bias[lane]) : -INFINITY;
    float m = v;
    #pragma unroll
    for (int d = 32; d >= 1; d >>= 1) m = fmaxf(m, __shfl_xor(m, d));
    float e = ch ? expf(v - m) : 0.f;
    float s = e;
    #pragma unroll
    for (int d = 32; d >= 1; d >>= 1) s += __shfl_xor(s, d);
    float lse = m + logf(s);
    if (ch) z[(size_t)node * OUT_CH + lane] = v - lse;
}

extern "C" void kernel_launch(void* const* d_in, const int* in_sizes, int n_in,
                              void* d_out, int out_size, void* d_ws, size_t ws_size,
                              hipStream_t stream) {
    const int*   edge_index = (const int*)d_in[0];
    const float* features   = (const float*)d_in[1];
    const float* eweights   = (const float*)d_in[2];
    const float* weight     = (const float*)d_in[3];
    const float* bias       = (const float*)d_in[4];

    const int* src = edge_index;            // edge_index[0, :]
    const int* dst = edge_index + N_EDGES;  // edge_index[1, :]

    float* out = (float*)d_out;

    // Workspace layout (bytes):
    //   xw (bf16, LD=64) @ 0 : 50000*64*2 = 6,400,000
    //   counts  @ 9,600,000 : NB*4
    //   base    @ 9,608,000 : NB*4
    //   cursor  @ 9,616,000 : NB*4
    //   epack   @ 9,624,000 : 12,800,000   (ends 22,424,000)
    //   wfrag   @ 22,424,000 : 49,152
    char* ws = (char*)d_ws;
    unsigned short* xw    = (unsigned short*)(ws + 0);
    int*   counts = (int*)  (ws + 9600000);
    int*   base   = (int*)  (ws + 9608000);
    int*   cursor = (int*)  (ws + 9616000);
    int2*  epack  = (int2*) (ws + 9624000);
    unsigned short* wfrag = (unsigned short*)(ws + 22424000);

    hipMemsetAsync(counts, 0, NB * sizeof(int), stream);
    hipMemsetAsync(d_out, 0, (size_t)N_NODES * OUT_CH * sizeof(float), stream);

    // 0) pre-format B fragments (once per launch)
    prep_bfrag<<<(IN_CH * OUT_CH / 4 + 255) / 256, 256, 0, stream>>>(weight, wfrag);

    // 1) xw = features @ weight  (bf16 MFMA, bf16 output)
    gemm_mfma<<<(N_TILES + 3) / 4, 256, 0, stream>>>(features, wfrag, xw);

    // 2) bucket binning (coarse, write-coalesced) + in-bucket sort
    bucket_hist<<<256, 256, 0, stream>>>(dst, counts);
    bucket_scan<<<1, 1024, 0, stream>>>(counts, base, cursor);
    bin_edges<<<(N_EDGES + ETILE - 1) / ETILE, 512, 0, stream>>>(src, dst, eweights,
                                                                 cursor, epack);
    sort_bucket<<<NB, 256, 0, stream>>>(base, cursor, epack);

    // 3) segmented reduction (wave per 128-edge chunk, paired half-wave streams)
    {
        int nWaves  = (N_EDGES + CHUNK - 1) / CHUNK;   // 12500
        int nBlocks = (nWaves + 3) / 4;
        seg_aggregate<<<nBlocks, 256, 0, stream>>>(epack, xw, out);
    }
    // 4) bias + log-softmax
    lsm_rows<<<(N_NODES + 3) / 4, 256, 0, stream>>>(out, bias);
}